// Round 1
// baseline (1602.472 us; speedup 1.0000x reference)
//
#include <hip/hip_runtime.h>
#include <math.h>

#define NB 16
#define NC 64
#define NH 256
#define NW 256
#define NM 12          // MODES
#define NJ 24          // 2*MODES ky modes (top 0..11, bottom 244..255)
#define NMODE 288      // NJ*NM
#define TPI256 0.024543692606170254f  // 2*pi/256

// ---- workspace layout (float offsets) ----
#define WS_STATS   0                       // 128 (sum[64], sumsq[64])
#define WS_STATS2  128                     // 128 (a[64], b[64])
#define WS_EW      256                     // [12][256][2]  = 6144   e^{-2pi i kx w/256} (cos,sin)
#define WS_EH      (WS_EW + 6144)          // [24][256][2]  = 12288  e^{-2pi i ky h/256} (cos,sin)
#define WS_XW      (WS_EH + 12288)         // [B][C][H][12][2] = 6291456
#define WS_XF      (WS_XW + 6291456)       // [B*C][288][2]    = 589824
#define WS_F       (WS_XF + 589824)        // [B][288][64][2]  = 589824
#define WS_Y1      (WS_F  + 589824)        // [B][C][H][12][2] = 6291456
#define WS_TOTAL   (WS_Y1 + 6291456)       // = 13781248 floats = 55.1 MB

// ---------------- K0: tables + zero stats ----------------
__global__ __launch_bounds__(256) void k0_init(float* __restrict__ ws) {
    int t = blockIdx.x * 256 + threadIdx.x;
    if (t < 128) ws[WS_STATS + t] = 0.f;
    if (t < 12 * 256) {
        int kx = t >> 8, w = t & 255;
        float ang = (float)((kx * w) & 255) * TPI256;
        float s, c; sincosf(ang, &s, &c);
        ws[WS_EW + t * 2] = c; ws[WS_EW + t * 2 + 1] = s;
    }
    if (t < 24 * 256) {
        int j = t >> 8, h = t & 255;
        int ky = (j < 12) ? j : (232 + j);
        float ang = (float)((ky * h) & 255) * TPI256;
        float s, c; sincosf(ang, &s, &c);
        ws[WS_EH + t * 2] = c; ws[WS_EH + t * 2 + 1] = s;
    }
}

// ---------------- K1: forward DFT along W (12 modes) ----------------
// grid = 8192 blocks, each handles 32 rows of x (row = flat over B*C*H)
__global__ __launch_bounds__(256) void k1_dftw(const float* __restrict__ x,
                                               float* __restrict__ ws) {
    __shared__ float xs[32 * 260];   // padded rows (+4 floats) to spread banks
    const float* ew = ws + WS_EW;
    float* xw = ws + WS_XW;
    int t = threadIdx.x;
    int rowbase = blockIdx.x * 32;
    const float4* src = (const float4*)(x + (size_t)rowbase * 256);
#pragma unroll
    for (int k = 0; k < 8; k++) {
        int g = t + 256 * k;          // float4 index in tile (32*64)
        int r = g >> 6, q = g & 63;
        ((float4*)(xs + r * 260))[q] = src[g];
    }
    __syncthreads();
    for (int item = t; item < 384; item += 256) {
        int r = item / 12, kx = item - r * 12;
        const float4* xr = (const float4*)(xs + r * 260);
        const float4* ewr = (const float4*)(ew + kx * 512);
        float are = 0.f, aim = 0.f;
#pragma unroll 4
        for (int q = 0; q < 64; q++) {
            float4 xv = xr[q];
            float4 e0 = ewr[2 * q];      // c0 s0 c1 s1
            float4 e1 = ewr[2 * q + 1];  // c2 s2 c3 s3
            are += xv.x * e0.x + xv.y * e0.z + xv.z * e1.x + xv.w * e1.z;
            aim -= xv.x * e0.y + xv.y * e0.w + xv.z * e1.y + xv.w * e1.w;
        }
        int R = rowbase + r;
        ((float2*)xw)[R * 12 + kx] = make_float2(are, aim);
    }
}

// ---------------- K2: DFT along H (24 modes) ----------------
// grid = 1024 blocks (b*64+c)
__global__ __launch_bounds__(256) void k2_dfth(float* __restrict__ ws) {
    __shared__ float sxw[256 * 24];  // [h][kx][2]
    int t = threadIdx.x;
    int bc = blockIdx.x;
    const float* eh = ws + WS_EH;
    const float4* src = (const float4*)(ws + WS_XW + (size_t)bc * 6144);
#pragma unroll
    for (int k = 0; k < 6; k++) ((float4*)sxw)[t + 256 * k] = src[t + 256 * k];
    __syncthreads();
    float2* xf = (float2*)(ws + WS_XF) + (size_t)bc * 288;
    for (int m = t; m < 288; m += 256) {
        int j = m / 12, kx = m - j * 12;
        const float2* ej = (const float2*)(eh + j * 512);
        float re = 0.f, im = 0.f;
#pragma unroll 4
        for (int h = 0; h < 256; h++) {
            float2 e = ej[h];                          // cos, sin
            float2 xv = ((const float2*)sxw)[h * 12 + kx];
            re += xv.x * e.x + xv.y * e.y;             // (xr+ixi)(c-is)
            im += xv.y * e.x - xv.x * e.y;
        }
        xf[m] = make_float2(re, im);
    }
}

// ---------------- K3: per-mode channel mix ----------------
// grid = 288 blocks (mode m = j*12+kx)
__global__ __launch_bounds__(256) void k3_mix(const float* __restrict__ w1,
                                              const float* __restrict__ w2,
                                              float* __restrict__ ws) {
    __shared__ float swg[4096 * 2];  // [i][o] complex
    __shared__ float sx[1024 * 2];   // [b][i] complex
    int m = blockIdx.x;
    int j = m / 12, kx = m - j * 12;
    int xm = (j < 12) ? j : (j - 12);
    const float* wsrc = (j < 12) ? w1 : w2;
    int t = threadIdx.x;
#pragma unroll
    for (int rep = 0; rep < 16; rep++) {
        int p = t + 256 * rep;       // p = i*64+o
        ((float2*)swg)[p] = ((const float2*)wsrc)[p * 144 + xm * 12 + kx];
    }
    const float2* xfp = (const float2*)(ws + WS_XF);
#pragma unroll
    for (int rep = 0; rep < 4; rep++) {
        int q = t + 256 * rep;       // q = b*64+i
        ((float2*)sx)[q] = xfp[q * 288 + m];
    }
    __syncthreads();
    int o = t & 63, bg = t >> 6;
    float2 acc[4];
#pragma unroll
    for (int bb = 0; bb < 4; bb++) acc[bb] = make_float2(0.f, 0.f);
    for (int i = 0; i < 64; i++) {
        float2 wv = ((const float2*)swg)[i * 64 + o];
#pragma unroll
        for (int bb = 0; bb < 4; bb++) {
            float2 xv = ((const float2*)sx)[(bb * 4 + bg) * 64 + i];
            acc[bb].x += xv.x * wv.x - xv.y * wv.y;
            acc[bb].y += xv.x * wv.y + xv.y * wv.x;
        }
    }
    float2* F = (float2*)(ws + WS_F);
#pragma unroll
    for (int bb = 0; bb < 4; bb++) {
        int b = bb * 4 + bg;
        F[(b * 288 + m) * 64 + o] = acc[bb];
    }
}

// ---------------- K4: inverse DFT along H ----------------
// grid = 1024 blocks (b*64+o), thread = h
__global__ __launch_bounds__(256) void k4_idfth(float* __restrict__ ws) {
    __shared__ float2 sf[288];
    int t = threadIdx.x;
    int bo = blockIdx.x;
    int b = bo >> 6, o = bo & 63;
    const float2* F = (const float2*)(ws + WS_F);
    for (int m = t; m < 288; m += 256) sf[m] = F[(b * 288 + m) * 64 + o];
    __syncthreads();
    int h = t;
    float yr[12], yi[12];
#pragma unroll
    for (int kx = 0; kx < 12; kx++) { yr[kx] = 0.f; yi[kx] = 0.f; }
    for (int j = 0; j < 24; j++) {
        int ky = (j < 12) ? j : (232 + j);
        float ang = (float)((ky * h) & 255) * TPI256;
        float s, c; sincosf(ang, &s, &c);
#pragma unroll
        for (int kx = 0; kx < 12; kx++) {
            float2 f = sf[j * 12 + kx];
            yr[kx] += f.x * c - f.y * s;   // (Fr+iFi)(c+is)
            yi[kx] += f.x * s + f.y * c;
        }
    }
    float4* y1 = (float4*)(ws + WS_Y1 + ((size_t)bo * 256 + h) * 24);
    y1[0] = make_float4(yr[0], yi[0], yr[1], yi[1]);
    y1[1] = make_float4(yr[2], yi[2], yr[3], yi[3]);
    y1[2] = make_float4(yr[4], yi[4], yr[5], yi[5]);
    y1[3] = make_float4(yr[6], yi[6], yr[7], yi[7]);
    y1[4] = make_float4(yr[8], yi[8], yr[9], yi[9]);
    y1[5] = make_float4(yr[10], yi[10], yr[11], yi[11]);
}

// ---------------- K5: fused irfft(W) + 1x1 conv + bias -> y (pre-BN) ----------------
// grid = 4096 blocks (b*256+h), thread = w
__global__ __launch_bounds__(256) void k5_fuse(const float* __restrict__ x,
                                               const float* __restrict__ wc,
                                               const float* __restrict__ bcv,
                                               const float* __restrict__ ws,
                                               float* __restrict__ out) {
    __shared__ float swc[4096];      // wc[o][i]
    __shared__ float sy1[64 * 24];   // [o][kx][2]
    __shared__ float sbc[64];
    int t = threadIdx.x;
    int bh = blockIdx.x;
    int b = bh >> 8, h = bh & 255;
#pragma unroll
    for (int k = 0; k < 16; k++) swc[t + 256 * k] = wc[t + 256 * k];
    if (t < 64) sbc[t] = bcv[t];
    const float* y1b = ws + WS_Y1 + ((size_t)b * 64 * 256 + h) * 24;
#pragma unroll
    for (int k = 0; k < 6; k++) {
        int f = t + 256 * k;
        int o = f / 24, r = f - o * 24;
        sy1[f] = y1b[(size_t)o * 6144 + r];
    }
    __syncthreads();
    int w = t;
    // x row into registers
    float xr[64];
    const float* xp = x + ((size_t)b * 64 * 256 + h) * 256 + w;
#pragma unroll
    for (int i = 0; i < 64; i++) xr[i] = xp[(size_t)i * 65536];
    // twiddles (doubled) for inverse W transform: e^{+2pi i kx w/256}
    float cw2[12], sw2[12];
#pragma unroll
    for (int kx = 1; kx < 12; kx++) {
        float ang = (float)((kx * w) & 255) * TPI256;
        float s, c; sincosf(ang, &s, &c);
        cw2[kx] = 2.f * c; sw2[kx] = 2.f * s;
    }
    float* outp = out + ((size_t)b * 64 * 256 + h) * 256 + w;
    const float inv = 1.f / 65536.f;
    for (int o = 0; o < 64; o++) {
        const float4* yo4 = (const float4*)(sy1 + o * 24);
        float4 a0 = yo4[0], a1 = yo4[1], a2 = yo4[2];
        float4 a3 = yo4[3], a4 = yo4[4], a5 = yo4[5];
        float spec = a0.x
            + (a0.z * cw2[1] - a0.w * sw2[1])
            + (a1.x * cw2[2] - a1.y * sw2[2])
            + (a1.z * cw2[3] - a1.w * sw2[3])
            + (a2.x * cw2[4] - a2.y * sw2[4])
            + (a2.z * cw2[5] - a2.w * sw2[5])
            + (a3.x * cw2[6] - a3.y * sw2[6])
            + (a3.z * cw2[7] - a3.w * sw2[7])
            + (a4.x * cw2[8] - a4.y * sw2[8])
            + (a4.z * cw2[9] - a4.w * sw2[9])
            + (a5.x * cw2[10] - a5.y * sw2[10])
            + (a5.z * cw2[11] - a5.w * sw2[11]);
        float acc = sbc[o] + spec * inv;
        const float4* wo = (const float4*)(swc + o * 64);
#pragma unroll
        for (int ii = 0; ii < 16; ii++) {
            float4 wv = wo[ii];
            acc += xr[4 * ii] * wv.x + xr[4 * ii + 1] * wv.y
                 + xr[4 * ii + 2] * wv.z + xr[4 * ii + 3] * wv.w;
        }
        outp[(size_t)o * 65536] = acc;
    }
}

// ---------------- K6: per-channel sum / sumsq ----------------
// grid = 1024 blocks (b*64+o): one 256KB plane each
__global__ __launch_bounds__(256) void k6_stats(const float* __restrict__ y,
                                                float* __restrict__ ws) {
    int t = threadIdx.x;
    int ob = blockIdx.x;
    const float4* p = (const float4*)(y + (size_t)ob * 65536);
    float s = 0.f, q = 0.f;
#pragma unroll 8
    for (int k = 0; k < 64; k++) {
        float4 v = p[t + 256 * k];
        s += v.x + v.y + v.z + v.w;
        q += v.x * v.x + v.y * v.y + v.z * v.z + v.w * v.w;
    }
#pragma unroll
    for (int m = 32; m; m >>= 1) { s += __shfl_xor(s, m); q += __shfl_xor(q, m); }
    __shared__ float red[8];
    int wid = t >> 6;
    if ((t & 63) == 0) { red[wid * 2] = s; red[wid * 2 + 1] = q; }
    __syncthreads();
    if (t == 0) {
        s = red[0] + red[2] + red[4] + red[6];
        q = red[1] + red[3] + red[5] + red[7];
        int o = ob & 63;
        atomicAdd(ws + WS_STATS + o, s);
        atomicAdd(ws + WS_STATS + 64 + o, q);
    }
}

// ---------------- K6b: finalize BN coefficients ----------------
__global__ void k6b_final(const float* __restrict__ gamma,
                          const float* __restrict__ beta,
                          float* __restrict__ ws) {
    int o = threadIdx.x;
    if (o < 64) {
        const float n = 1048576.f;  // B*H*W
        float mean = ws[WS_STATS + o] / n;
        float var = ws[WS_STATS + 64 + o] / n - mean * mean;
        float a = gamma[o] * rsqrtf(var + 1e-5f);
        ws[WS_STATS2 + o] = a;
        ws[WS_STATS2 + 64 + o] = beta[o] - mean * a;
    }
}

// ---------------- K7: BN + exact GELU, in-place on d_out ----------------
__global__ __launch_bounds__(256) void k7_bngelu(float* __restrict__ y,
                                                 const float* __restrict__ ws) {
    const float* st = ws + WS_STATS2;
    size_t idx = (size_t)blockIdx.x * 256 + threadIdx.x;
    size_t stride = (size_t)gridDim.x * 256;
    float4* p = (float4*)y;
    for (size_t i = idx; i < 16777216u; i += stride) {
        int o = (int)((i >> 14) & 63);
        float a = st[o], bb = st[64 + o];
        float4 v = p[i];
        float z0 = a * v.x + bb, z1 = a * v.y + bb, z2 = a * v.z + bb, z3 = a * v.w + bb;
        v.x = 0.5f * z0 * (1.f + erff(z0 * 0.70710678118654752f));
        v.y = 0.5f * z1 * (1.f + erff(z1 * 0.70710678118654752f));
        v.z = 0.5f * z2 * (1.f + erff(z2 * 0.70710678118654752f));
        v.w = 0.5f * z3 * (1.f + erff(z3 * 0.70710678118654752f));
        p[i] = v;
    }
}

extern "C" void kernel_launch(void* const* d_in, const int* in_sizes, int n_in,
                              void* d_out, int out_size, void* d_ws, size_t ws_size,
                              hipStream_t stream) {
    (void)in_sizes; (void)n_in; (void)out_size;
    if (ws_size < (size_t)WS_TOTAL * sizeof(float)) return;  // insufficient scratch
    const float* x     = (const float*)d_in[0];
    const float* w1    = (const float*)d_in[1];
    const float* w2    = (const float*)d_in[2];
    const float* wc    = (const float*)d_in[3];
    const float* bcv   = (const float*)d_in[4];
    const float* gamma = (const float*)d_in[5];
    const float* beta  = (const float*)d_in[6];
    float* out = (float*)d_out;
    float* ws = (float*)d_ws;

    k0_init  <<<24,   256, 0, stream>>>(ws);
    k1_dftw  <<<8192, 256, 0, stream>>>(x, ws);
    k2_dfth  <<<1024, 256, 0, stream>>>(ws);
    k3_mix   <<<288,  256, 0, stream>>>(w1, w2, ws);
    k4_idfth <<<1024, 256, 0, stream>>>(ws);
    k5_fuse  <<<4096, 256, 0, stream>>>(x, wc, bcv, ws, out);
    k6_stats <<<1024, 256, 0, stream>>>(out, ws);
    k6b_final<<<1,    64,  0, stream>>>(gamma, beta, ws);
    k7_bngelu<<<4096, 256, 0, stream>>>(out, ws);
}

// Round 3
// 1361.653 us; speedup vs baseline: 1.1769x; 1.1769x over previous
//
#include <hip/hip_runtime.h>
#include <math.h>

#define NB 16
#define NC 64
#define NH 256
#define NW 256
#define NM 12          // MODES
#define NJ 24          // ky modes (top 0..11, bottom 244..255)
#define NMODE 288      // NJ*NM
#define TPI256 0.024543692606170254f  // 2*pi/256

// ---- workspace layout (float offsets) ----
#define WS_STATS   0                       // 128 (sum[64], sumsq[64])
#define WS_STATS2  128                     // 128 (a[64], b[64])
#define WS_EW      256                     // [12][2][256] = 6144   cos-plane / sin-plane of e^{2pi kx w/256}
#define WS_EH      (WS_EW + 6144)          // [24][2][256] = 12288  cos/sin planes of e^{2pi ky h/256}
#define WS_XW      (WS_EH + 12288)         // [B][C][H][12][2] = 6291456
#define WS_XF      (WS_XW + 6291456)       // [B*C][288][2]    = 589824
#define WS_F       (WS_XF + 589824)        // [B][288][64][2]  = 589824
#define WS_Y1      (WS_F  + 589824)        // [B][C][H][12][2] = 6291456
#define WS_TOTAL   (WS_Y1 + 6291456)       // = 13781248 floats = 55.1 MB

// ---------------- K0: tables (plane layout) + zero stats ----------------
__global__ __launch_bounds__(256) void k0_init(float* __restrict__ ws) {
    int t = blockIdx.x * 256 + threadIdx.x;
    if (t < 128) ws[WS_STATS + t] = 0.f;
    if (t < 12 * 256) {
        int kx = t >> 8, w = t & 255;
        float ang = (float)((kx * w) & 255) * TPI256;
        float s, c; sincosf(ang, &s, &c);
        ws[WS_EW + kx * 512 + w] = c;
        ws[WS_EW + kx * 512 + 256 + w] = s;
    }
    if (t < 24 * 256) {
        int j = t >> 8, h = t & 255;
        int ky = (j < 12) ? j : (232 + j);
        float ang = (float)((ky * h) & 255) * TPI256;
        float s, c; sincosf(ang, &s, &c);
        ws[WS_EH + j * 512 + h] = c;
        ws[WS_EH + j * 512 + 256 + h] = s;
    }
}

// ---------------- K1: forward DFT along W (12 modes) ----------------
// Register-tiled: thread = (wseg&3, kxg 0..3, r8 0..15); 8 rows x 3 kx x 64 w each.
// grid = 2048 blocks of 128 rows.
__global__ __launch_bounds__(256) void k1_dftw(const float* __restrict__ x,
                                               float* __restrict__ ws) {
    __shared__ float xs[128 * 68];        // [row][64 w + pad4], 16B-aligned rows
    __shared__ float tws[12 * 136];       // [kx][plane(2)][64+pad4]
    int t = threadIdx.x;
    int wseg = t & 3, kxg = (t >> 2) & 3, r8 = t >> 4;
    int rowbase = blockIdx.x * 128;
    float ar[8][3], ai[8][3];
#pragma unroll
    for (int j = 0; j < 8; ++j)
#pragma unroll
        for (int i = 0; i < 3; ++i) { ar[j][i] = 0.f; ai[j][i] = 0.f; }

    for (int pass = 0; pass < 4; ++pass) {
        if (pass) __syncthreads();
        // stage x chunk: 128 rows x 64 floats
        {
            const float* xg = x + (size_t)rowbase * 256 + pass * 64;
            int q = t & 15, r0 = t >> 4;
#pragma unroll
            for (int i = 0; i < 8; ++i) {
                int row = r0 + 16 * i;
                *(float4*)(xs + row * 68 + q * 4) =
                    *(const float4*)(xg + (size_t)row * 256 + q * 4);
            }
        }
        // stage twiddle chunk: [12][2][64]
        for (int f = t; f < 384; f += 256) {
            int kx = f >> 5, plane = (f >> 4) & 1, q = f & 15;
            *(float4*)(tws + kx * 136 + plane * 68 + q * 4) =
                *(const float4*)(ws + WS_EW + kx * 512 + plane * 256 + pass * 64 + q * 4);
        }
        __syncthreads();
        // compute: 4 w-quads of this thread's wseg
#pragma unroll
        for (int wq = 0; wq < 4; ++wq) {
            int woff = wseg * 16 + wq * 4;
            float4 xv[8];
#pragma unroll
            for (int j = 0; j < 8; ++j)
                xv[j] = *(const float4*)(xs + (r8 + 16 * j) * 68 + woff);
#pragma unroll
            for (int i = 0; i < 3; ++i) {
                int kx = kxg * 3 + i;
                float4 c4 = *(const float4*)(tws + kx * 136 + woff);
                float4 s4 = *(const float4*)(tws + kx * 136 + 68 + woff);
#pragma unroll
                for (int j = 0; j < 8; ++j) {
                    ar[j][i] += xv[j].x * c4.x + xv[j].y * c4.y + xv[j].z * c4.z + xv[j].w * c4.w;
                    ai[j][i] -= xv[j].x * s4.x + xv[j].y * s4.y + xv[j].z * s4.z + xv[j].w * s4.w;
                }
            }
        }
    }
    // reduce over the 4 w-segments (lanes t^1, t^2)
#pragma unroll
    for (int j = 0; j < 8; ++j)
#pragma unroll
        for (int i = 0; i < 3; ++i) {
            ar[j][i] += __shfl_xor(ar[j][i], 1);
            ar[j][i] += __shfl_xor(ar[j][i], 2);
            ai[j][i] += __shfl_xor(ai[j][i], 1);
            ai[j][i] += __shfl_xor(ai[j][i], 2);
        }
    if (wseg == 0) {
        float2* xw = (float2*)(ws + WS_XW);
#pragma unroll
        for (int j = 0; j < 8; ++j) {
            size_t row = rowbase + r8 + 16 * j;
#pragma unroll
            for (int i = 0; i < 3; ++i) {
                int kx = kxg * 3 + i;
                xw[row * 12 + kx] = make_float2(ar[j][i], ai[j][i]);
            }
        }
    }
}

// ---------------- K2: DFT along H (24 modes) ----------------
// block = 288 threads, one per (j,kx); EH staged in LDS chunks; Xw tile in LDS.
__global__ __launch_bounds__(288) void k2_dfth(float* __restrict__ ws) {
    __shared__ float sxw[256 * 28];   // [h][24 + pad4] (16B-aligned rows)
    __shared__ float ehs[24 * 136];   // [j][plane(2)][64+pad4]
    int t = threadIdx.x;
    int bc = blockIdx.x;
    // stage Xw tile: 256 rows x 24 floats (contiguous) = 1536 float4
    {
        const float4* src = (const float4*)(ws + WS_XW + (size_t)bc * 6144);
        for (int f = t; f < 1536; f += 288) {
            int row = f / 6, q = f - row * 6;
            *(float4*)(sxw + row * 28 + q * 4) = src[f];
        }
    }
    int j = t / 12, kx = t - j * 12;
    float re = 0.f, im = 0.f;
    for (int pass = 0; pass < 4; ++pass) {
        __syncthreads();
        for (int f = t; f < 768; f += 288) {
            int jj = f >> 5, plane = (f >> 4) & 1, q = f & 15;
            *(float4*)(ehs + jj * 136 + plane * 68 + q * 4) =
                *(const float4*)(ws + WS_EH + jj * 512 + plane * 256 + pass * 64 + q * 4);
        }
        __syncthreads();
#pragma unroll 4
        for (int hh = 0; hh < 64; hh += 4) {
            float4 c4 = *(const float4*)(ehs + j * 136 + hh);
            float4 s4 = *(const float4*)(ehs + j * 136 + 68 + hh);
            int hbase = pass * 64 + hh;
            float2 x0 = *(const float2*)(sxw + (hbase + 0) * 28 + kx * 2);
            float2 x1 = *(const float2*)(sxw + (hbase + 1) * 28 + kx * 2);
            float2 x2 = *(const float2*)(sxw + (hbase + 2) * 28 + kx * 2);
            float2 x3 = *(const float2*)(sxw + (hbase + 3) * 28 + kx * 2);
            re += x0.x * c4.x + x0.y * s4.x + x1.x * c4.y + x1.y * s4.y
                + x2.x * c4.z + x2.y * s4.z + x3.x * c4.w + x3.y * s4.w;
            im += x0.y * c4.x - x0.x * s4.x + x1.y * c4.y - x1.x * s4.y
                + x2.y * c4.z - x2.x * s4.z + x3.y * c4.w - x3.x * s4.w;
        }
    }
    ((float2*)(ws + WS_XF))[(size_t)bc * 288 + t] = make_float2(re, im);
}

// ---------------- K3: per-mode channel mix ----------------
__global__ __launch_bounds__(256) void k3_mix(const float* __restrict__ w1,
                                              const float* __restrict__ w2,
                                              float* __restrict__ ws) {
    __shared__ float swg[4096 * 2];  // [i][o] complex
    __shared__ float sx[1024 * 2];   // [b][i] complex
    int m = blockIdx.x;
    int j = m / 12, kx = m - j * 12;
    int xm = (j < 12) ? j : (j - 12);
    const float* wsrc = (j < 12) ? w1 : w2;
    int t = threadIdx.x;
#pragma unroll
    for (int rep = 0; rep < 16; rep++) {
        int p = t + 256 * rep;       // p = i*64+o
        ((float2*)swg)[p] = ((const float2*)wsrc)[p * 144 + xm * 12 + kx];
    }
    const float2* xfp = (const float2*)(ws + WS_XF);
#pragma unroll
    for (int rep = 0; rep < 4; rep++) {
        int q = t + 256 * rep;       // q = b*64+i
        ((float2*)sx)[q] = xfp[q * 288 + m];
    }
    __syncthreads();
    int o = t & 63, bg = t >> 6;
    float2 acc[4];
#pragma unroll
    for (int bb = 0; bb < 4; bb++) acc[bb] = make_float2(0.f, 0.f);
    for (int i = 0; i < 64; i++) {
        float2 wv = ((const float2*)swg)[i * 64 + o];
#pragma unroll
        for (int bb = 0; bb < 4; bb++) {
            float2 xv = ((const float2*)sx)[(bb * 4 + bg) * 64 + i];
            acc[bb].x += xv.x * wv.x - xv.y * wv.y;
            acc[bb].y += xv.x * wv.y + xv.y * wv.x;
        }
    }
    float2* F = (float2*)(ws + WS_F);
#pragma unroll
    for (int bb = 0; bb < 4; bb++) {
        int b = bb * 4 + bg;
        F[((size_t)b * 288 + m) * 64 + o] = acc[bb];
    }
}

// ---------------- K4: inverse DFT along H (table-driven) ----------------
__global__ __launch_bounds__(256) void k4_idfth(float* __restrict__ ws) {
    __shared__ float2 sf[288];
    int t = threadIdx.x;
    int bo = blockIdx.x;
    int b = bo >> 6, o = bo & 63;
    const float2* F = (const float2*)(ws + WS_F);
    for (int m = t; m < 288; m += 256) sf[m] = F[((size_t)b * 288 + m) * 64 + o];
    __syncthreads();
    int h = t;
    float yr[12], yi[12];
#pragma unroll
    for (int kx = 0; kx < 12; kx++) { yr[kx] = 0.f; yi[kx] = 0.f; }
    const float* ehp = ws + WS_EH;
    for (int j = 0; j < 24; j++) {
        float c = ehp[j * 512 + h];
        float s = ehp[j * 512 + 256 + h];
#pragma unroll
        for (int kx = 0; kx < 12; kx++) {
            float2 f = sf[j * 12 + kx];
            yr[kx] += f.x * c - f.y * s;   // (Fr+iFi)(c+is)
            yi[kx] += f.x * s + f.y * c;
        }
    }
    float4* y1 = (float4*)(ws + WS_Y1 + ((size_t)bo * 256 + h) * 24);
    y1[0] = make_float4(yr[0], yi[0], yr[1], yi[1]);
    y1[1] = make_float4(yr[2], yi[2], yr[3], yi[3]);
    y1[2] = make_float4(yr[4], yi[4], yr[5], yi[5]);
    y1[3] = make_float4(yr[6], yi[6], yr[7], yi[7]);
    y1[4] = make_float4(yr[8], yi[8], yr[9], yi[9]);
    y1[5] = make_float4(yr[10], yi[10], yr[11], yi[11]);
}

// ---------------- K5: fused irfft(W) + 1x1 conv + bias -> y (pre-BN) ----------------
// No LDS: y1/wc/bc reads are block-uniform (scalarize to s_load); x row in VGPRs.
__global__ __launch_bounds__(256) void k5_fuse(const float* __restrict__ x,
                                               const float* __restrict__ wc,
                                               const float* __restrict__ bcv,
                                               const float* __restrict__ ws,
                                               float* __restrict__ out) {
    int t = threadIdx.x;
    int bh = blockIdx.x;
    int b = bh >> 8, h = bh & 255;
    int w = t;
    const float* xp = x + ((size_t)b * 64 * 256 + h) * 256 + w;
    float xr[64];
#pragma unroll
    for (int i = 0; i < 64; ++i) xr[i] = xp[(size_t)i * 65536];
    float cw2[12], sw2[12];
#pragma unroll
    for (int kx = 1; kx < 12; ++kx) {
        cw2[kx] = 2.f * ws[WS_EW + kx * 512 + w];
        sw2[kx] = 2.f * ws[WS_EW + kx * 512 + 256 + w];
    }
    const float inv = 1.f / 65536.f;
    float* outp = out + ((size_t)b * 64 * 256 + h) * 256 + w;
    const float* y1base = ws + WS_Y1 + (size_t)b * 64 * 6144 + h * 24;
    for (int o = 0; o < 64; ++o) {
        const float* yo = y1base + (size_t)o * 6144;
        float spec = yo[0];
#pragma unroll
        for (int kx = 1; kx < 12; ++kx)
            spec += yo[2 * kx] * cw2[kx] - yo[2 * kx + 1] * sw2[kx];
        float acc = bcv[o] + spec * inv;
        const float* wo = wc + o * 64;
#pragma unroll
        for (int ii = 0; ii < 64; ++ii) acc += xr[ii] * wo[ii];
        outp[(size_t)o * 65536] = acc;
    }
}

// ---------------- K6: per-channel sum / sumsq ----------------
__global__ __launch_bounds__(256) void k6_stats(const float* __restrict__ y,
                                                float* __restrict__ ws) {
    int t = threadIdx.x;
    int ob = blockIdx.x;
    const float4* p = (const float4*)(y + (size_t)ob * 65536);
    float s = 0.f, q = 0.f;
#pragma unroll 8
    for (int k = 0; k < 64; k++) {
        float4 v = p[t + 256 * k];
        s += v.x + v.y + v.z + v.w;
        q += v.x * v.x + v.y * v.y + v.z * v.z + v.w * v.w;
    }
#pragma unroll
    for (int m = 32; m; m >>= 1) { s += __shfl_xor(s, m); q += __shfl_xor(q, m); }
    __shared__ float red[8];
    int wid = t >> 6;
    if ((t & 63) == 0) { red[wid * 2] = s; red[wid * 2 + 1] = q; }
    __syncthreads();
    if (t == 0) {
        s = red[0] + red[2] + red[4] + red[6];
        q = red[1] + red[3] + red[5] + red[7];
        int o = ob & 63;
        atomicAdd(ws + WS_STATS + o, s);
        atomicAdd(ws + WS_STATS + 64 + o, q);
    }
}

// ---------------- K6b: finalize BN coefficients ----------------
__global__ void k6b_final(const float* __restrict__ gamma,
                          const float* __restrict__ beta,
                          float* __restrict__ ws) {
    int o = threadIdx.x;
    if (o < 64) {
        const float n = 1048576.f;  // B*H*W
        float mean = ws[WS_STATS + o] / n;
        float var = ws[WS_STATS + 64 + o] / n - mean * mean;
        float a = gamma[o] * rsqrtf(var + 1e-5f);
        ws[WS_STATS2 + o] = a;
        ws[WS_STATS2 + 64 + o] = beta[o] - mean * a;
    }
}

// ---------------- K7: BN + exact GELU, in-place on d_out ----------------
__global__ __launch_bounds__(256) void k7_bngelu(float* __restrict__ y,
                                                 const float* __restrict__ ws) {
    const float* st = ws + WS_STATS2;
    size_t idx = (size_t)blockIdx.x * 256 + threadIdx.x;
    size_t stride = (size_t)gridDim.x * 256;
    float4* p = (float4*)y;
    for (size_t i = idx; i < 16777216u; i += stride) {
        int o = (int)((i >> 14) & 63);
        float a = st[o], bb = st[64 + o];
        float4 v = p[i];
        float z0 = a * v.x + bb, z1 = a * v.y + bb, z2 = a * v.z + bb, z3 = a * v.w + bb;
        v.x = 0.5f * z0 * (1.f + erff(z0 * 0.70710678118654752f));
        v.y = 0.5f * z1 * (1.f + erff(z1 * 0.70710678118654752f));
        v.z = 0.5f * z2 * (1.f + erff(z2 * 0.70710678118654752f));
        v.w = 0.5f * z3 * (1.f + erff(z3 * 0.70710678118654752f));
        p[i] = v;
    }
}

extern "C" void kernel_launch(void* const* d_in, const int* in_sizes, int n_in,
                              void* d_out, int out_size, void* d_ws, size_t ws_size,
                              hipStream_t stream) {
    (void)in_sizes; (void)n_in; (void)out_size;
    if (ws_size < (size_t)WS_TOTAL * sizeof(float)) return;
    const float* x     = (const float*)d_in[0];
    const float* w1    = (const float*)d_in[1];
    const float* w2    = (const float*)d_in[2];
    const float* wc    = (const float*)d_in[3];
    const float* bcv   = (const float*)d_in[4];
    const float* gamma = (const float*)d_in[5];
    const float* beta  = (const float*)d_in[6];
    float* out = (float*)d_out;
    float* ws = (float*)d_ws;

    k0_init  <<<24,   256, 0, stream>>>(ws);
    k1_dftw  <<<2048, 256, 0, stream>>>(x, ws);
    k2_dfth  <<<1024, 288, 0, stream>>>(ws);
    k3_mix   <<<288,  256, 0, stream>>>(w1, w2, ws);
    k4_idfth <<<1024, 256, 0, stream>>>(ws);
    k5_fuse  <<<4096, 256, 0, stream>>>(x, wc, bcv, ws, out);
    k6_stats <<<1024, 256, 0, stream>>>(out, ws);
    k6b_final<<<1,    64,  0, stream>>>(gamma, beta, ws);
    k7_bngelu<<<4096, 256, 0, stream>>>(out, ws);
}